// Round 10
// baseline (387.727 us; speedup 1.0000x reference)
//
#include <hip/hip_runtime.h>
#include <hip/hip_bf16.h>
#include <stdint.h>

// ---------- types ----------
typedef __attribute__((ext_vector_type(8)))  short bf16x8;
typedef __attribute__((ext_vector_type(4)))  float f32x4;
typedef __attribute__((ext_vector_type(16))) float f32x16;
typedef __attribute__((ext_vector_type(4)))  float float4v;
typedef __attribute__((ext_vector_type(8)))  unsigned short u16x8;

#define MFMA16(a,b,c) __builtin_amdgcn_mfma_f32_16x16x32_bf16((a),(b),(c),0,0,0)
#define MFMA32(a,b,c) __builtin_amdgcn_mfma_f32_32x32x16_bf16((a),(b),(c),0,0,0)

__device__ __forceinline__ unsigned short f2bf(float f) {
    unsigned int u = __builtin_bit_cast(unsigned int, f);
    u = (u + 0x7fffu + ((u >> 16) & 1u)) >> 16;
    return (unsigned short)u;
}

__device__ __forceinline__ void gload_lds16(const void* g, void* l) {
    __builtin_amdgcn_global_load_lds(
        (const __attribute__((address_space(1))) void*)g,
        (__attribute__((address_space(3))) void*)l, 16, 0, 0);
}

template<int N> __device__ __forceinline__ void waitvm() {}  // N<0: no wait
template<> __device__ __forceinline__ void waitvm<6>() { asm volatile("s_waitcnt vmcnt(6)" ::: "memory"); }
template<> __device__ __forceinline__ void waitvm<0>() { asm volatile("s_waitcnt vmcnt(0)" ::: "memory"); }

// ---------- fp32 -> bf16 convert ----------
__global__ void cvt_f32_bf16(const float* __restrict__ in, unsigned short* __restrict__ out, long n) {
    long i = ((long)blockIdx.x * blockDim.x + threadIdx.x) * 8;
    long stride = (long)gridDim.x * blockDim.x * 8;
    for (; i < n; i += stride) {
        float4v v0 = *(const float4v*)(in + i);
        float4v v1 = *(const float4v*)(in + i + 4);
        u16x8 o;
        o[0] = f2bf(v0[0]); o[1] = f2bf(v0[1]); o[2] = f2bf(v0[2]); o[3] = f2bf(v0[3]);
        o[4] = f2bf(v1[0]); o[5] = f2bf(v1[1]); o[6] = f2bf(v1[2]); o[7] = f2bf(v1[3]);
        *(u16x8*)(out + i) = o;
    }
}

// ---------- GEMM1: z = H(bf16) @ VT(bf16)^T, 256x256 tile ----------
// Round-9 schedule UNCHANGED (8 phases / 2 K-tiles, vmcnt(6) at P4/P8, legal
// tail-prefetches, cross-wave visibility rule respected). This round swaps the
// MFMA shape 16x16x32 -> 32x32x16 (matrix-pipe ceiling 2176 -> 2495 TF).
// Fragment math:
//   A-frag (mf in 0..1 per quadrant, ks in 0..3): row = wr*128 + QM*64 + mf*32
//     + (lane&31), k = ks*16 + (lane>>5)*8 -> logical granule 2*ks + (lane>>5),
//     phys = logical ^ (row&7) = ^ (lane&7). One b128 per frag.
//   B-frag (nf = QN, ks): row(n) = wc*64 + QN*32 + (lane&31), same k/granule.
//   C/D (verified m74/m101): col = lane&31, row = (reg&3)+8*(reg>>2)+4*(lane>>5).
// Per phase: 8 MFMA (2 mf x 4 ks), 8 A-reads or 4 B-reads -- identical DS
// counts, stage slots, and ledger as round 9.

#define STAGE_A(nA_, k0n, h, l) \
    gload_lds16(pA + ((l)*128 + (h)*64) * 4096L + (k0n), (nA_) + dA0 + ((l)*128 + (h)*64) * 64)
#define STAGE_B(nB_, k0n, h, l) \
    gload_lds16(pB + ((l)*128 + (h)*32) * 4096L + (k0n), (nB_) + dB0 + ((l)*128 + (h)*32) * 64)

#define LDA32(dst_, sA_, QM) do { \
    _Pragma("unroll") for (int mf = 0; mf < 2; ++mf) \
      _Pragma("unroll") for (int ks = 0; ks < 4; ++ks) \
        dst_[mf][ks] = *(const bf16x8*)((sA_) + ((wr*128 + (QM)*64 + mf*32 + l31) << 6) \
                                        + (((2*ks + g32) ^ x7) << 3)); } while (0)
#define LDB32(dst_, sB_, QN) do { \
    _Pragma("unroll") for (int ks = 0; ks < 4; ++ks) \
        dst_[ks] = *(const bf16x8*)((sB_) + ((wc*64 + (QN)*32 + l31) << 6) \
                                    + (((2*ks + g32) ^ x7) << 3)); } while (0)

#define DOMFMA32(QM, QN, aset_, bset_) do { __builtin_amdgcn_s_setprio(1); \
    _Pragma("unroll") for (int ks = 0; ks < 4; ++ks) \
      _Pragma("unroll") for (int mf = 0; mf < 2; ++mf) \
        acc32[(QM)*2+mf][QN] = MFMA32(aset_[mf][ks], bset_[ks], acc32[(QM)*2+mf][QN]); \
    __builtin_amdgcn_s_setprio(0); } while (0)

#define BAR1() do { __builtin_amdgcn_s_barrier(); \
    asm volatile("s_waitcnt lgkmcnt(0)" ::: "memory"); \
    __builtin_amdgcn_sched_barrier(0); } while (0)
#define BAR2() do { __builtin_amdgcn_s_barrier(); \
    __builtin_amdgcn_sched_barrier(0); } while (0)

#define ITER8(K1, K2, K3, S2, S3, V4, V8) do { \
  /*P1*/ LDA32(aE, bA0, 0); LDB32(bb0, bB0, 0); \
         STAGE_A(bA1, K1, 1, 0); STAGE_A(bA1, K1, 1, 1); \
         BAR1(); DOMFMA32(0, 0, aE, bb0); LDB32(bb1, bB0, 1); BAR2(); \
  /*P2*/ if (S2) { STAGE_A(bA0, K2, 0, 0); STAGE_A(bA0, K2, 0, 1); } \
         BAR1(); DOMFMA32(0, 1, aE, bb1); LDA32(aO, bA0, 1); BAR2(); \
  /*P3*/ if (S2) { STAGE_B(bB0, K2, 0, 0); STAGE_B(bB0, K2, 0, 1); } \
         BAR1(); DOMFMA32(1, 1, aO, bb1); BAR2(); \
  /*P4*/ if (S2) { STAGE_B(bB0, K2, 1, 0); STAGE_B(bB0, K2, 1, 1); } \
         BAR1(); DOMFMA32(1, 0, aO, bb0); waitvm<V4>(); BAR2(); \
  /*P5*/ LDA32(aE, bA1, 0); LDB32(bb0, bB1, 0); \
         if (S2) { STAGE_A(bA0, K2, 1, 0); STAGE_A(bA0, K2, 1, 1); } \
         BAR1(); DOMFMA32(0, 0, aE, bb0); LDB32(bb1, bB1, 1); BAR2(); \
  /*P6*/ if (S3) { STAGE_A(bA1, K3, 0, 0); STAGE_A(bA1, K3, 0, 1); } \
         BAR1(); DOMFMA32(0, 1, aE, bb1); LDA32(aO, bA1, 1); BAR2(); \
  /*P7*/ if (S3) { STAGE_B(bB1, K3, 0, 0); STAGE_B(bB1, K3, 0, 1); } \
         BAR1(); DOMFMA32(1, 1, aO, bb1); BAR2(); \
  /*P8*/ if (S3) { STAGE_B(bB1, K3, 1, 0); STAGE_B(bB1, K3, 1, 1); } \
         BAR1(); DOMFMA32(1, 0, aO, bb0); waitvm<V8>(); BAR2(); \
} while (0)

__global__ __launch_bounds__(512, 2) void gemm1_8ph(const unsigned short* __restrict__ A,  // [16384][4096]
                                                    const unsigned short* __restrict__ B,  // [2048][4096]
                                                    unsigned short* __restrict__ Z) {      // [16384][2048]
    __shared__ __align__(16) unsigned short lds[65536];   // 128 KiB

    const int tid   = threadIdx.x;
    const int lane  = tid & 63;
    const int wid   = tid >> 6;
    const int wr    = wid >> 2;          // 0..1
    const int wc    = wid & 3;           // 0..3
    const int l31   = lane & 31;
    const int g32   = lane >> 5;         // 0..1
    const int x7    = lane & 7;

    const int  bid = blockIdx.x;
    const long m0  = (long)(bid >> 3) * 256;
    const long n0  = (long)(bid & 7) * 256;

    const int q8    = tid >> 3;
    const int granA = (((tid & 7) ^ (q8 & 7)) << 3);
    const unsigned short* pA = A + (m0 + q8) * 4096L + granA;
    const int rB0   = (q8 & 31) + ((q8 >> 5) << 6);
    const unsigned short* pB = B + (n0 + rB0) * 4096L + granA;
    const int dA0   = (wid * 8) * 64;
    const int dB0   = ((wid & 3) * 8 + ((wid >> 2) << 6)) * 64;

    f32x16 acc32[4][2] = {};
    bf16x8 aE[2][4], aO[2][4], bb0[4], bb1[4];

    unsigned short* bA0 = lds;
    unsigned short* bB0 = lds + 16384;
    unsigned short* bA1 = lds + 32768;
    unsigned short* bB1 = lds + 49152;

    // ---- prologue: t0 {Ah0,Bh0,Bh1,Ah1}, t1 {Ah0,Bh0,Bh1} = 14 issues ----
    STAGE_A(bA0, 0, 0, 0);  STAGE_A(bA0, 0, 0, 1);    // t0 Ah0
    STAGE_B(bB0, 0, 0, 0);  STAGE_B(bB0, 0, 0, 1);    // t0 Bh0
    STAGE_B(bB0, 0, 1, 0);  STAGE_B(bB0, 0, 1, 1);    // t0 Bh1
    STAGE_A(bA0, 0, 1, 0);  STAGE_A(bA0, 0, 1, 1);    // t0 Ah1
    STAGE_A(bA1, 64, 0, 0); STAGE_A(bA1, 64, 0, 1);   // t1 Ah0
    STAGE_B(bB1, 64, 0, 0); STAGE_B(bB1, 64, 0, 1);   // t1 Bh0
    STAGE_B(bB1, 64, 1, 0); STAGE_B(bB1, 64, 1, 1);   // t1 Bh1
    waitvm<6>();            // retires all of t0's 8 issues (per wave)
    BAR2();                 // makes every wave's retirement visible

    // ---- main loop: iters 0..30 (tiles 0..61 computed, 2..63 staged) ----
    for (int i = 0; i < 31; ++i) {
        ITER8((2 * i + 1) * 64, (2 * i + 2) * 64, (2 * i + 3) * 64, true, true, 6, 6);
    }
    // ---- final iter (tiles 62,63): stage only P1's Ah1(63); drain at P4 ----
    ITER8(63 * 64, 0, 0, false, false, 0, -1);

    // ---- epilogue: z bf16 store; 32x32 C/D: col=lane&31, row=(reg&3)+8*(reg>>2)+4*(lane>>5) ----
    #pragma unroll
    for (int mf = 0; mf < 4; ++mf) {
        #pragma unroll
        for (int nf = 0; nf < 2; ++nf) {
            const long cb = n0 + wc * 64 + nf * 32 + l31;
            #pragma unroll
            for (int reg = 0; reg < 16; ++reg) {
                const long rb = m0 + wr * 128 + mf * 32 + (reg & 3) + 8 * (reg >> 2) + 4 * g32;
                Z[rb * 2048L + cb] = f2bf(acc32[mf][nf][reg]);
            }
        }
    }
}

// ---------- GEMM2: grouped up-projection (write-BW floor, unchanged) ----------
#define U_PAD 80

__global__ __launch_bounds__(256) void gemm2(const unsigned short* __restrict__ Z,  // [16384][2048] bf16
                                             const float* __restrict__ U,           // [32][128][64] f32
                                             float* __restrict__ out) {             // [16384][4096] f32
    __shared__ __align__(16) unsigned short lU[128 * U_PAD];

    const int tid  = threadIdx.x;
    const int lane = tid & 63;
    const int wid  = tid >> 6;
    const int g    = blockIdx.x & 31;
    const long m0  = (long)(blockIdx.x >> 5) * 64;

    const float* ug = U + (long)g * (128 * 64);
    for (int i = tid; i < (128 * 64) / 4; i += 256) {
        const int r = i >> 4;
        const int c = (i << 2) & 63;
        float4v v = *(const float4v*)(ug + i * 4);
        unsigned short* d = &lU[r * U_PAD + c];
        d[0] = f2bf(v[0]); d[1] = f2bf(v[1]); d[2] = f2bf(v[2]); d[3] = f2bf(v[3]);
    }
    __syncthreads();

    const long mrow = m0 + wid * 16 + (lane & 15);
    const unsigned short* zrow = Z + mrow * 2048L + g * 64 + ((lane >> 4) << 3);
    const bf16x8 a0 = *(const bf16x8*)(zrow);
    const bf16x8 a1 = *(const bf16x8*)(zrow + 32);

    f32x4 acc[8] = {};
    const int blds = (lane & 15);
    const int kofs = (lane >> 4) << 3;
    #pragma unroll
    for (int ni = 0; ni < 8; ++ni) {
        const bf16x8 c0 = *(const bf16x8*)&lU[(ni * 16 + blds) * U_PAD + kofs];
        const bf16x8 c1 = *(const bf16x8*)&lU[(ni * 16 + blds) * U_PAD + 32 + kofs];
        acc[ni] = MFMA16(a0, c0, acc[ni]);
        acc[ni] = MFMA16(a1, c1, acc[ni]);
    }

    const long mb = m0 + wid * 16 + ((lane >> 4) << 2);
    const long cb = (long)g * 128 + (lane & 15);
    #pragma unroll
    for (int ni = 0; ni < 8; ++ni)
        #pragma unroll
        for (int j = 0; j < 4; ++j)
            out[(mb + j) * 4096L + cb + ni * 16] = acc[ni][j];
}

// ---------- launch ----------
extern "C" void kernel_launch(void* const* d_in, const int* in_sizes, int n_in,
                              void* d_out, int out_size, void* d_ws, size_t ws_size,
                              hipStream_t stream) {
    const float* hs = (const float*)d_in[0];   // [4,4096,4096] fp32
    const float* vt = (const float*)d_in[1];   // [2048,4096]   fp32
    const float* uw = (const float*)d_in[2];   // [32,128,64]   fp32
    float* out = (float*)d_out;

    unsigned short* hs_bf = (unsigned short*)d_ws;            // 67108864 bf16
    unsigned short* vt_bf = hs_bf + 67108864L;                //  8388608 bf16
    unsigned short* z_bf  = vt_bf + 8388608L;                 // 33554432 bf16

    cvt_f32_bf16<<<2048, 256, 0, stream>>>(hs, hs_bf, 67108864L);
    cvt_f32_bf16<<<512, 256, 0, stream>>>(vt, vt_bf, 8388608L);

    // GEMM1: (16384/256) x (2048/256) = 64 x 8 = 512 blocks, 512 threads
    gemm1_8ph<<<512, 512, 0, stream>>>(hs_bf, vt_bf, z_bf);

    // GEMM2: (16384/64) x 32 groups = 8192 blocks
    gemm2<<<8192, 256, 0, stream>>>(z_bf, uw, out);
}

// Round 11
// 362.285 us; speedup vs baseline: 1.0702x; 1.0702x over previous
//
#include <hip/hip_runtime.h>
#include <hip/hip_bf16.h>
#include <stdint.h>

// ---------- types ----------
typedef __attribute__((ext_vector_type(8)))  short bf16x8;
typedef __attribute__((ext_vector_type(4)))  float f32x4;
typedef __attribute__((ext_vector_type(4)))  float float4v;
typedef __attribute__((ext_vector_type(8)))  unsigned short u16x8;

#define MFMA16(a,b,c) __builtin_amdgcn_mfma_f32_16x16x32_bf16((a),(b),(c),0,0,0)

__device__ __forceinline__ unsigned short f2bf(float f) {
    unsigned int u = __builtin_bit_cast(unsigned int, f);
    u = (u + 0x7fffu + ((u >> 16) & 1u)) >> 16;
    return (unsigned short)u;
}

__device__ __forceinline__ void gload_lds16(const void* g, void* l) {
    __builtin_amdgcn_global_load_lds(
        (const __attribute__((address_space(1))) void*)g,
        (__attribute__((address_space(3))) void*)l, 16, 0, 0);
}

template<int N> __device__ __forceinline__ void waitvm() {}  // N<0: no wait
template<> __device__ __forceinline__ void waitvm<6>() { asm volatile("s_waitcnt vmcnt(6)" ::: "memory"); }
template<> __device__ __forceinline__ void waitvm<4>() { asm volatile("s_waitcnt vmcnt(4)" ::: "memory"); }
template<> __device__ __forceinline__ void waitvm<0>() { asm volatile("s_waitcnt vmcnt(0)" ::: "memory"); }

// ---------- fp32 -> bf16 convert ----------
__global__ void cvt_f32_bf16(const float* __restrict__ in, unsigned short* __restrict__ out, long n) {
    long i = ((long)blockIdx.x * blockDim.x + threadIdx.x) * 8;
    long stride = (long)gridDim.x * blockDim.x * 8;
    for (; i < n; i += stride) {
        float4v v0 = *(const float4v*)(in + i);
        float4v v1 = *(const float4v*)(in + i + 4);
        u16x8 o;
        o[0] = f2bf(v0[0]); o[1] = f2bf(v0[1]); o[2] = f2bf(v0[2]); o[3] = f2bf(v0[3]);
        o[4] = f2bf(v1[0]); o[5] = f2bf(v1[1]); o[6] = f2bf(v1[2]); o[7] = f2bf(v1[3]);
        *(u16x8*)(out + i) = o;
    }
}

// ---------- GEMM1: z = H(bf16) @ VT(bf16)^T, 256x256 tile, 16x16x32 MFMA ----------
// Round-9 stage map; reads FULLY tail-moved; waits shifted P4->P3, P8->P7.
//
// Stage map (iter i computes tiles 2i,2i+1; stages 2i+2,2i+3):
//   P1: Ah1(2i+1)->bA1.h1   P2: Ah0(2i+2)->bA0.h0  P3: Bh0(2i+2)->bB0.h0
//   P4: Bh1(2i+2)->bB0.h1   P5: Ah1(2i+2)->bA0.h1  P6: Ah0(2i+3)->bA1.h0
//   P7: Bh0(2i+3)->bB1.h0   P8: Bh1(2i+3)->bB1.h1
// Waits: W3 = vmcnt(4) end-P3 (retires thru P1(i)); W7 = vmcnt(4) end-P7
// (retires thru P5(i)). All ds_reads are TAILS (after DOMFMA, before BAR2):
//   P8-tail: aE<-bA0.h0 [P2(i)], b0<-bB0.h0 [P3(i)]   (covered W7(i), vis P7.BAR2)
//   P1-tail: b1<-bB0.h1 [P4(i-1)]                     (covered W7(i-1))
//   P2-tail: aO<-bA0.h1 [P5(i-1)]                     (covered W7(i-1))
//   P4-tail: aE<-bA1.h0 [P6(i-1)], b0<-bB1.h0 [P7(i-1)] (covered W3(i), vis P3.BAR2)
//   P5-tail: b1<-bB1.h1 [P8(i-1)]                     (covered W3(i))
//   P6-tail: aO<-bA1.h1 [P1(i)]                       (covered W3(i))
// Overwrite gaps: every tail-read drains at the NEXT phase's BAR1 lgkm(0),
// >=1 full phase before its region restages (P8t->P2/P3; P1t->P4; P2t->P5;
// P4t->P6/P7; P5t->P8; P6t->P1(i+1)). Cross-wave visibility rule respected:
// every tail sits after the covering wait's barrier.

#define STAGE_A(nA_, k0n, h, l) \
    gload_lds16(pA + ((l)*128 + (h)*64) * 4096L + (k0n), (nA_) + dA0 + ((l)*128 + (h)*64) * 64)
#define STAGE_B(nB_, k0n, h, l) \
    gload_lds16(pB + ((l)*128 + (h)*32) * 4096L + (k0n), (nB_) + dB0 + ((l)*128 + (h)*32) * 64)

#define LDA(dst_, sA_, QM) do { _Pragma("unroll") for (int mi = 0; mi < 4; ++mi) { \
    dst_[mi][0] = *(const bf16x8*)((sA_) + ((wr*128 + (QM)*64 + mi*16 + lan15) << 6) + g0); \
    dst_[mi][1] = *(const bf16x8*)((sA_) + ((wr*128 + (QM)*64 + mi*16 + lan15) << 6) + (g0 ^ 32)); } } while (0)
#define LDB(dst_, sB_, QN) do { _Pragma("unroll") for (int ni = 0; ni < 2; ++ni) { \
    dst_[ni][0] = *(const bf16x8*)((sB_) + ((wc*64 + (QN)*32 + ni*16 + lan15) << 6) + g0); \
    dst_[ni][1] = *(const bf16x8*)((sB_) + ((wc*64 + (QN)*32 + ni*16 + lan15) << 6) + (g0 ^ 32)); } } while (0)

#define DOMFMA(QM, QN, aset_, bset_) do { __builtin_amdgcn_s_setprio(1); \
    _Pragma("unroll") for (int mi = 0; mi < 4; ++mi) \
      _Pragma("unroll") for (int ni = 0; ni < 2; ++ni) { \
        acc[(QM)*4+mi][(QN)*2+ni] = MFMA16(aset_[mi][0], bset_[ni][0], acc[(QM)*4+mi][(QN)*2+ni]); \
        acc[(QM)*4+mi][(QN)*2+ni] = MFMA16(aset_[mi][1], bset_[ni][1], acc[(QM)*4+mi][(QN)*2+ni]); } \
    __builtin_amdgcn_s_setprio(0); } while (0)

#define BAR1() do { __builtin_amdgcn_s_barrier(); \
    asm volatile("s_waitcnt lgkmcnt(0)" ::: "memory"); \
    __builtin_amdgcn_sched_barrier(0); } while (0)
#define BAR2() do { __builtin_amdgcn_s_barrier(); \
    __builtin_amdgcn_sched_barrier(0); } while (0)

#define ITER8(K1, K2, K3, S2, S3, T8, V3, V7) do { \
  /*P1*/ STAGE_A(bA1, K1, 1, 0); STAGE_A(bA1, K1, 1, 1); \
         BAR1(); DOMFMA(0, 0, aE, b0); LDB(b1, bB0, 1); BAR2(); \
  /*P2*/ if (S2) { STAGE_A(bA0, K2, 0, 0); STAGE_A(bA0, K2, 0, 1); } \
         BAR1(); DOMFMA(0, 1, aE, b1); LDA(aO, bA0, 1); BAR2(); \
  /*P3*/ if (S2) { STAGE_B(bB0, K2, 0, 0); STAGE_B(bB0, K2, 0, 1); } \
         BAR1(); DOMFMA(1, 1, aO, b1); waitvm<V3>(); BAR2(); \
  /*P4*/ if (S2) { STAGE_B(bB0, K2, 1, 0); STAGE_B(bB0, K2, 1, 1); } \
         BAR1(); DOMFMA(1, 0, aO, b0); LDA(aE, bA1, 0); LDB(b0, bB1, 0); BAR2(); \
  /*P5*/ if (S2) { STAGE_A(bA0, K2, 1, 0); STAGE_A(bA0, K2, 1, 1); } \
         BAR1(); DOMFMA(0, 0, aE, b0); LDB(b1, bB1, 1); BAR2(); \
  /*P6*/ if (S3) { STAGE_A(bA1, K3, 0, 0); STAGE_A(bA1, K3, 0, 1); } \
         BAR1(); DOMFMA(0, 1, aE, b1); LDA(aO, bA1, 1); BAR2(); \
  /*P7*/ if (S3) { STAGE_B(bB1, K3, 0, 0); STAGE_B(bB1, K3, 0, 1); } \
         BAR1(); DOMFMA(1, 1, aO, b1); waitvm<V7>(); BAR2(); \
  /*P8*/ if (S3) { STAGE_B(bB1, K3, 1, 0); STAGE_B(bB1, K3, 1, 1); } \
         BAR1(); DOMFMA(1, 0, aO, b0); \
         if (T8) { LDA(aE, bA0, 0); LDB(b0, bB0, 0); } BAR2(); \
} while (0)

__global__ __launch_bounds__(512, 2) void gemm1_8ph(const unsigned short* __restrict__ A,  // [16384][4096]
                                                    const unsigned short* __restrict__ B,  // [2048][4096]
                                                    unsigned short* __restrict__ Z) {      // [16384][2048]
    __shared__ __align__(16) unsigned short lds[65536];   // 128 KiB

    const int tid   = threadIdx.x;
    const int lane  = tid & 63;
    const int wid   = tid >> 6;
    const int wr    = wid >> 2;          // 0..1
    const int wc    = wid & 3;           // 0..3
    const int lan15 = lane & 15;
    const int g0    = (((lane >> 4) ^ (lane & 7)) << 3);

    const int  bid = blockIdx.x;
    const long m0  = (long)(bid >> 3) * 256;
    const long n0  = (long)(bid & 7) * 256;

    const int q8    = tid >> 3;
    const int granA = (((tid & 7) ^ (q8 & 7)) << 3);
    const unsigned short* pA = A + (m0 + q8) * 4096L + granA;
    const int rB0   = (q8 & 31) + ((q8 >> 5) << 6);
    const unsigned short* pB = B + (n0 + rB0) * 4096L + granA;
    const int dA0   = (wid * 8) * 64;
    const int dB0   = ((wid & 3) * 8 + ((wid >> 2) << 6)) * 64;

    f32x4 acc[8][4] = {};
    bf16x8 aE[4][2], aO[4][2], b0[2][2], b1[2][2];

    unsigned short* bA0 = lds;
    unsigned short* bB0 = lds + 16384;
    unsigned short* bA1 = lds + 32768;
    unsigned short* bB1 = lds + 49152;

    // ---- prologue: t0 {Ah0,Bh0,Bh1,Ah1}, t1 {Ah0,Bh0,Bh1} = 14 issues ----
    STAGE_A(bA0, 0, 0, 0);  STAGE_A(bA0, 0, 0, 1);    // t0 Ah0  (#1,2)
    STAGE_B(bB0, 0, 0, 0);  STAGE_B(bB0, 0, 0, 1);    // t0 Bh0  (#3,4)
    STAGE_B(bB0, 0, 1, 0);  STAGE_B(bB0, 0, 1, 1);    // t0 Bh1  (#5,6)
    STAGE_A(bA0, 0, 1, 0);  STAGE_A(bA0, 0, 1, 1);    // t0 Ah1  (#7,8)
    STAGE_A(bA1, 64, 0, 0); STAGE_A(bA1, 64, 0, 1);   // t1 Ah0  (#9,10)
    STAGE_B(bB1, 64, 0, 0); STAGE_B(bB1, 64, 0, 1);   // t1 Bh0  (#11,12)
    STAGE_B(bB1, 64, 1, 0); STAGE_B(bB1, 64, 1, 1);   // t1 Bh1  (#13,14)
    waitvm<6>();            // retires t0 (#1-8) in every wave
    BAR2();                 // visibility barrier
    LDA(aE, bA0, 0); LDB(b0, bB0, 0);   // "P0-tail": t0 Ah0/Bh0 fragments

    // ---- main loop: iters 0..30 (tiles 0..61 computed, 2..63 staged) ----
    for (int i = 0; i < 31; ++i) {
        ITER8((2 * i + 1) * 64, (2 * i + 2) * 64, (2 * i + 3) * 64,
              true, true, true, 4, 4);
    }
    // ---- final iter (tiles 62,63): stage only P1's Ah1(63); drain at P3 ----
    ITER8(63 * 64, 0, 0, false, false, false, 0, -1);

    // ---- epilogue: z bf16 store; C/D col = lane&15 (n), row = (lane>>4)*4+j ----
    const int rq = (lane >> 4) << 2;
    #pragma unroll
    for (int mi = 0; mi < 8; ++mi) {
        #pragma unroll
        for (int ni = 0; ni < 4; ++ni) {
            const long mb  = m0 + wr * 128 + mi * 16 + rq;
            const long nb2 = n0 + wc * 64 + ni * 16 + lan15;
            #pragma unroll
            for (int j = 0; j < 4; ++j)
                Z[(mb + j) * 2048L + nb2] = f2bf(acc[mi][ni][j]);
        }
    }
}

// ---------- GEMM2: grouped up-projection (write-BW floor, unchanged) ----------
#define U_PAD 80

__global__ __launch_bounds__(256) void gemm2(const unsigned short* __restrict__ Z,  // [16384][2048] bf16
                                             const float* __restrict__ U,           // [32][128][64] f32
                                             float* __restrict__ out) {             // [16384][4096] f32
    __shared__ __align__(16) unsigned short lU[128 * U_PAD];

    const int tid  = threadIdx.x;
    const int lane = tid & 63;
    const int wid  = tid >> 6;
    const int g    = blockIdx.x & 31;
    const long m0  = (long)(blockIdx.x >> 5) * 64;

    const float* ug = U + (long)g * (128 * 64);
    for (int i = tid; i < (128 * 64) / 4; i += 256) {
        const int r = i >> 4;
        const int c = (i << 2) & 63;
        float4v v = *(const float4v*)(ug + i * 4);
        unsigned short* d = &lU[r * U_PAD + c];
        d[0] = f2bf(v[0]); d[1] = f2bf(v[1]); d[2] = f2bf(v[2]); d[3] = f2bf(v[3]);
    }
    __syncthreads();

    const long mrow = m0 + wid * 16 + (lane & 15);
    const unsigned short* zrow = Z + mrow * 2048L + g * 64 + ((lane >> 4) << 3);
    const bf16x8 a0 = *(const bf16x8*)(zrow);
    const bf16x8 a1 = *(const bf16x8*)(zrow + 32);

    f32x4 acc[8] = {};
    const int blds = (lane & 15);
    const int kofs = (lane >> 4) << 3;
    #pragma unroll
    for (int ni = 0; ni < 8; ++ni) {
        const bf16x8 c0 = *(const bf16x8*)&lU[(ni * 16 + blds) * U_PAD + kofs];
        const bf16x8 c1 = *(const bf16x8*)&lU[(ni * 16 + blds) * U_PAD + 32 + kofs];
        acc[ni] = MFMA16(a0, c0, acc[ni]);
        acc[ni] = MFMA16(a1, c1, acc[ni]);
    }

    const long mb = m0 + wid * 16 + ((lane >> 4) << 2);
    const long cb = (long)g * 128 + (lane & 15);
    #pragma unroll
    for (int ni = 0; ni < 8; ++ni)
        #pragma unroll
        for (int j = 0; j < 4; ++j)
            out[(mb + j) * 4096L + cb + ni * 16] = acc[ni][j];
}

// ---------- launch ----------
extern "C" void kernel_launch(void* const* d_in, const int* in_sizes, int n_in,
                              void* d_out, int out_size, void* d_ws, size_t ws_size,
                              hipStream_t stream) {
    const float* hs = (const float*)d_in[0];   // [4,4096,4096] fp32
    const float* vt = (const float*)d_in[1];   // [2048,4096]   fp32
    const float* uw = (const float*)d_in[2];   // [32,128,64]   fp32
    float* out = (float*)d_out;

    unsigned short* hs_bf = (unsigned short*)d_ws;            // 67108864 bf16
    unsigned short* vt_bf = hs_bf + 67108864L;                //  8388608 bf16
    unsigned short* z_bf  = vt_bf + 8388608L;                 // 33554432 bf16

    cvt_f32_bf16<<<2048, 256, 0, stream>>>(hs, hs_bf, 67108864L);
    cvt_f32_bf16<<<512, 256, 0, stream>>>(vt, vt_bf, 8388608L);

    // GEMM1: (16384/256) x (2048/256) = 64 x 8 = 512 blocks, 512 threads
    gemm1_8ph<<<512, 512, 0, stream>>>(hs_bf, vt_bf, z_bf);

    // GEMM2: (16384/64) x 32 groups = 8192 blocks
    gemm2<<<8192, 256, 0, stream>>>(z_bf, uw, out);
}

// Round 12
// 357.232 us; speedup vs baseline: 1.0854x; 1.0141x over previous
//
#include <hip/hip_runtime.h>
#include <hip/hip_bf16.h>
#include <stdint.h>

// ---------- types ----------
typedef __attribute__((ext_vector_type(8)))  short bf16x8;
typedef __attribute__((ext_vector_type(4)))  float f32x4;
typedef __attribute__((ext_vector_type(4)))  float float4v;
typedef __attribute__((ext_vector_type(8)))  unsigned short u16x8;

#define MFMA16(a,b,c) __builtin_amdgcn_mfma_f32_16x16x32_bf16((a),(b),(c),0,0,0)

__device__ __forceinline__ unsigned short f2bf(float f) {
    unsigned int u = __builtin_bit_cast(unsigned int, f);
    u = (u + 0x7fffu + ((u >> 16) & 1u)) >> 16;
    return (unsigned short)u;
}

__device__ __forceinline__ void gload_lds16(const void* g, void* l) {
    __builtin_amdgcn_global_load_lds(
        (const __attribute__((address_space(1))) void*)g,
        (__attribute__((address_space(3))) void*)l, 16, 0, 0);
}

template<int N> __device__ __forceinline__ void waitvm() {}  // N<0: no wait
template<> __device__ __forceinline__ void waitvm<6>() { asm volatile("s_waitcnt vmcnt(6)" ::: "memory"); }
template<> __device__ __forceinline__ void waitvm<4>() { asm volatile("s_waitcnt vmcnt(4)" ::: "memory"); }
template<> __device__ __forceinline__ void waitvm<0>() { asm volatile("s_waitcnt vmcnt(0)" ::: "memory"); }

// ---------- fp32 -> bf16 convert ----------
__global__ void cvt_f32_bf16(const float* __restrict__ in, unsigned short* __restrict__ out, long n) {
    long i = ((long)blockIdx.x * blockDim.x + threadIdx.x) * 8;
    long stride = (long)gridDim.x * blockDim.x * 8;
    for (; i < n; i += stride) {
        float4v v0 = *(const float4v*)(in + i);
        float4v v1 = *(const float4v*)(in + i + 4);
        u16x8 o;
        o[0] = f2bf(v0[0]); o[1] = f2bf(v0[1]); o[2] = f2bf(v0[2]); o[3] = f2bf(v0[3]);
        o[4] = f2bf(v1[0]); o[5] = f2bf(v1[1]); o[6] = f2bf(v1[2]); o[7] = f2bf(v1[3]);
        *(u16x8*)(out + i) = o;
    }
}

// ---------- GEMM1: z = H(bf16) @ VT(bf16)^T, 256x256 tile, 16x16x32 MFMA ----------
// SINGLE-BARRIER 8-phase schedule. Safety model: a wave issuing stage(p) has
// passed BAR(p-1) => all waves arrived BAR(p-1) => all executed lgkm(0) after
// BAR(p-2) => all drained tail-reads from phases <= p-3. Therefore stages may
// overwrite regions whose last read was >= 3 phases earlier. Stage map was
// shifted (A0.h0: P2->P3, A1.h0: P6->P7) so ALL restage gaps are exactly 3.
//
// Stage map (iter i computes u=2i, v=2i+1; stages u+2 -> bufs0, v+2 -> bufs1):
//   P1: Ah1(v)->A1.h1 [2]     P3: Ah0(u+2)->A0.h0, Bh0(u+2)->B0.h0 [4]
//   P4: Bh1(u+2)->B0.h1 [2]   P5: Ah1(u+2)->A0.h1 [2]
//   P7: Ah0(v+2)->A1.h0, Bh0(v+2)->B1.h0 [4]   P8: Bh1(v+2)->B1.h1 [2]
// Waits: W3 = vmcnt(4) end-P3 (outstanding = P3's 4; retires thru P1(i));
//        W7 = vmcnt(4) end-P7 (outstanding = P7's 4; retires thru P5(i)).
// Tails (after MFMA, before the NEXT phase's stage+barrier):
//   P1: b1<-B0.h1 [P4(i-1), cov W7(i-1)]     P2: aO<-A0.h1 [P5(i-1), cov W7(i-1)]
//   P4: aE<-A1.h0, b0<-B1.h0 [P7(i-1), cov W3(i)]
//   P5: b1<-B1.h1 [P8(i-1), cov W3(i)]       P6: aO<-A1.h1 [P1(i), cov W3(i)]
//   P8: aE<-A0.h0, b0<-B0.h0 [P3(i), cov W7(i)]
// Every tail sits after its covering wait's barrier (visibility); every
// stage->covering-wait spans >= 2 phases (HBM latency). Restage gaps
// (read-phase -> stage-phase) all = 3: A0.h0 P8->P3(+3), A0.h1 P2->P5,
// A1.h0 P4->P7, A1.h1 P6->P1', B0.h0 P8->P3, B0.h1 P1->P4, B1.h0 P4->P7,
// B1.h1 P5->P8.

#define STAGE_A(nA_, k0n, h, l) \
    gload_lds16(pA + ((l)*128 + (h)*64) * 4096L + (k0n), (nA_) + dA0 + ((l)*128 + (h)*64) * 64)
#define STAGE_B(nB_, k0n, h, l) \
    gload_lds16(pB + ((l)*128 + (h)*32) * 4096L + (k0n), (nB_) + dB0 + ((l)*128 + (h)*32) * 64)

#define LDA(dst_, sA_, QM) do { _Pragma("unroll") for (int mi = 0; mi < 4; ++mi) { \
    dst_[mi][0] = *(const bf16x8*)((sA_) + ((wr*128 + (QM)*64 + mi*16 + lan15) << 6) + g0); \
    dst_[mi][1] = *(const bf16x8*)((sA_) + ((wr*128 + (QM)*64 + mi*16 + lan15) << 6) + (g0 ^ 32)); } } while (0)
#define LDB(dst_, sB_, QN) do { _Pragma("unroll") for (int ni = 0; ni < 2; ++ni) { \
    dst_[ni][0] = *(const bf16x8*)((sB_) + ((wc*64 + (QN)*32 + ni*16 + lan15) << 6) + g0); \
    dst_[ni][1] = *(const bf16x8*)((sB_) + ((wc*64 + (QN)*32 + ni*16 + lan15) << 6) + (g0 ^ 32)); } } while (0)

#define DOMFMA(QM, QN, aset_, bset_) do { __builtin_amdgcn_s_setprio(1); \
    _Pragma("unroll") for (int mi = 0; mi < 4; ++mi) \
      _Pragma("unroll") for (int ni = 0; ni < 2; ++ni) { \
        acc[(QM)*4+mi][(QN)*2+ni] = MFMA16(aset_[mi][0], bset_[ni][0], acc[(QM)*4+mi][(QN)*2+ni]); \
        acc[(QM)*4+mi][(QN)*2+ni] = MFMA16(aset_[mi][1], bset_[ni][1], acc[(QM)*4+mi][(QN)*2+ni]); } \
    __builtin_amdgcn_s_setprio(0); } while (0)

// single barrier per phase: s_barrier -> lgkm(0) -> sched fence
#define BARX() do { __builtin_amdgcn_s_barrier(); \
    asm volatile("s_waitcnt lgkmcnt(0)" ::: "memory"); \
    __builtin_amdgcn_sched_barrier(0); } while (0)
// end-of-phase scheduling fence (keeps tails/waits from crossing into next stage)
#define SB() __builtin_amdgcn_sched_barrier(0)

#define ITER8(K1, K2, K3, S2, S3, T8, V3, V7) do { \
  /*P1*/ STAGE_A(bA1, K1, 1, 0); STAGE_A(bA1, K1, 1, 1); \
         BARX(); DOMFMA(0, 0, aE, b0); LDB(b1, bB0, 1); SB(); \
  /*P2*/ BARX(); DOMFMA(0, 1, aE, b1); LDA(aO, bA0, 1); SB(); \
  /*P3*/ if (S2) { STAGE_A(bA0, K2, 0, 0); STAGE_A(bA0, K2, 0, 1); \
                   STAGE_B(bB0, K2, 0, 0); STAGE_B(bB0, K2, 0, 1); } \
         BARX(); DOMFMA(1, 1, aO, b1); waitvm<V3>(); SB(); \
  /*P4*/ if (S2) { STAGE_B(bB0, K2, 1, 0); STAGE_B(bB0, K2, 1, 1); } \
         BARX(); DOMFMA(1, 0, aO, b0); LDA(aE, bA1, 0); LDB(b0, bB1, 0); SB(); \
  /*P5*/ if (S2) { STAGE_A(bA0, K2, 1, 0); STAGE_A(bA0, K2, 1, 1); } \
         BARX(); DOMFMA(0, 0, aE, b0); LDB(b1, bB1, 1); SB(); \
  /*P6*/ BARX(); DOMFMA(0, 1, aE, b1); LDA(aO, bA1, 1); SB(); \
  /*P7*/ if (S3) { STAGE_A(bA1, K3, 0, 0); STAGE_A(bA1, K3, 0, 1); \
                   STAGE_B(bB1, K3, 0, 0); STAGE_B(bB1, K3, 0, 1); } \
         BARX(); DOMFMA(1, 1, aO, b1); waitvm<V7>(); SB(); \
  /*P8*/ if (S3) { STAGE_B(bB1, K3, 1, 0); STAGE_B(bB1, K3, 1, 1); } \
         BARX(); DOMFMA(1, 0, aO, b0); \
         if (T8) { LDA(aE, bA0, 0); LDB(b0, bB0, 0); } SB(); \
} while (0)

__global__ __launch_bounds__(512, 2) void gemm1_8ph(const unsigned short* __restrict__ A,  // [16384][4096]
                                                    const unsigned short* __restrict__ B,  // [2048][4096]
                                                    unsigned short* __restrict__ Z) {      // [16384][2048]
    __shared__ __align__(16) unsigned short lds[65536];   // 128 KiB

    const int tid   = threadIdx.x;
    const int lane  = tid & 63;
    const int wid   = tid >> 6;
    const int wr    = wid >> 2;          // 0..1
    const int wc    = wid & 3;           // 0..3
    const int lan15 = lane & 15;
    const int g0    = (((lane >> 4) ^ (lane & 7)) << 3);

    const int  bid = blockIdx.x;
    const long m0  = (long)(bid >> 3) * 256;
    const long n0  = (long)(bid & 7) * 256;

    const int q8    = tid >> 3;
    const int granA = (((tid & 7) ^ (q8 & 7)) << 3);
    const unsigned short* pA = A + (m0 + q8) * 4096L + granA;
    const int rB0   = (q8 & 31) + ((q8 >> 5) << 6);
    const unsigned short* pB = B + (n0 + rB0) * 4096L + granA;
    const int dA0   = (wid * 8) * 64;
    const int dB0   = ((wid & 3) * 8 + ((wid >> 2) << 6)) * 64;

    f32x4 acc[8][4] = {};
    bf16x8 aE[4][2], aO[4][2], b0[2][2], b1[2][2];

    unsigned short* bA0 = lds;
    unsigned short* bB0 = lds + 16384;
    unsigned short* bA1 = lds + 32768;
    unsigned short* bB1 = lds + 49152;

    // ---- prologue: stage t0 fully + t1 {Ah0? no: A1.h0, B1.h0, B1.h1} ----
    // issue order: #1-2 A0.h0, #3-4 B0.h0, #5-6 B0.h1, #7-8 A0.h1,
    //              #9-10 A1.h0, #11-12 B1.h0, #13-14 B1.h1
    STAGE_A(bA0, 0, 0, 0);  STAGE_A(bA0, 0, 0, 1);
    STAGE_B(bB0, 0, 0, 0);  STAGE_B(bB0, 0, 0, 1);
    STAGE_B(bB0, 0, 1, 0);  STAGE_B(bB0, 0, 1, 1);
    STAGE_A(bA0, 0, 1, 0);  STAGE_A(bA0, 0, 1, 1);
    STAGE_A(bA1, 64, 0, 0); STAGE_A(bA1, 64, 0, 1);
    STAGE_B(bB1, 64, 0, 0); STAGE_B(bB1, 64, 0, 1);
    STAGE_B(bB1, 64, 1, 0); STAGE_B(bB1, 64, 1, 1);
    waitvm<6>();            // retires #1-8 (A0 full + B0 full) in every wave
    __builtin_amdgcn_s_barrier();       // visibility for all waves
    __builtin_amdgcn_sched_barrier(0);
    LDA(aE, bA0, 0); LDB(b0, bB0, 0);   // prologue tail (drains at P1's BARX)
    SB();
    // iter-0 coverage: P1-tail B0.h1 (#5-6) & P2-tail A0.h1 (#7-8) retired by
    // prologue vmcnt(6); P4-tail A1.h0/B1.h0 (#9-12) and P5-tail B1.h1 (#13-14)
    // retired by W3(0) = vmcnt(4) (leaves only P3(0)'s 4 issues).

    // ---- main loop: iters 0..30 (tiles 0..61 computed, 2..63 staged) ----
    for (int i = 0; i < 31; ++i) {
        ITER8((2 * i + 1) * 64, (2 * i + 2) * 64, (2 * i + 3) * 64,
              true, true, true, 4, 4);
    }
    // ---- final iter (tiles 62,63): stage only P1's Ah1(63); V3 drains ----
    ITER8(63 * 64, 0, 0, false, false, false, 0, -1);

    // ---- epilogue: z bf16 store; C/D col = lane&15 (n), row = (lane>>4)*4+j ----
    const int rq = (lane >> 4) << 2;
    #pragma unroll
    for (int mi = 0; mi < 8; ++mi) {
        #pragma unroll
        for (int ni = 0; ni < 4; ++ni) {
            const long mb  = m0 + wr * 128 + mi * 16 + rq;
            const long nb2 = n0 + wc * 64 + ni * 16 + lan15;
            #pragma unroll
            for (int j = 0; j < 4; ++j)
                Z[(mb + j) * 2048L + nb2] = f2bf(acc[mi][ni][j]);
        }
    }
}

// ---------- GEMM2: grouped up-projection (write-BW floor, unchanged) ----------
#define U_PAD 80

__global__ __launch_bounds__(256) void gemm2(const unsigned short* __restrict__ Z,  // [16384][2048] bf16
                                             const float* __restrict__ U,           // [32][128][64] f32
                                             float* __restrict__ out) {             // [16384][4096] f32
    __shared__ __align__(16) unsigned short lU[128 * U_PAD];

    const int tid  = threadIdx.x;
    const int lane = tid & 63;
    const int wid  = tid >> 6;
    const int g    = blockIdx.x & 31;
    const long m0  = (long)(blockIdx.x >> 5) * 64;

    const float* ug = U + (long)g * (128 * 64);
    for (int i = tid; i < (128 * 64) / 4; i += 256) {
        const int r = i >> 4;
        const int c = (i << 2) & 63;
        float4v v = *(const float4v*)(ug + i * 4);
        unsigned short* d = &lU[r * U_PAD + c];
        d[0] = f2bf(v[0]); d[1] = f2bf(v[1]); d[2] = f2bf(v[2]); d[3] = f2bf(v[3]);
    }
    __syncthreads();

    const long mrow = m0 + wid * 16 + (lane & 15);
    const unsigned short* zrow = Z + mrow * 2048L + g * 64 + ((lane >> 4) << 3);
    const bf16x8 a0 = *(const bf16x8*)(zrow);
    const bf16x8 a1 = *(const bf16x8*)(zrow + 32);

    f32x4 acc[8] = {};
    const int blds = (lane & 15);
    const int kofs = (lane >> 4) << 3;
    #pragma unroll
    for (int ni = 0; ni < 8; ++ni) {
        const bf16x8 c0 = *(const bf16x8*)&lU[(ni * 16 + blds) * U_PAD + kofs];
        const bf16x8 c1 = *(const bf16x8*)&lU[(ni * 16 + blds) * U_PAD + 32 + kofs];
        acc[ni] = MFMA16(a0, c0, acc[ni]);
        acc[ni] = MFMA16(a1, c1, acc[ni]);
    }

    const long mb = m0 + wid * 16 + ((lane >> 4) << 2);
    const long cb = (long)g * 128 + (lane & 15);
    #pragma unroll
    for (int ni = 0; ni < 8; ++ni)
        #pragma unroll
        for (int j = 0; j < 4; ++j)
            out[(mb + j) * 4096L + cb + ni * 16] = acc[ni][j];
}

// ---------- launch ----------
extern "C" void kernel_launch(void* const* d_in, const int* in_sizes, int n_in,
                              void* d_out, int out_size, void* d_ws, size_t ws_size,
                              hipStream_t stream) {
    const float* hs = (const float*)d_in[0];   // [4,4096,4096] fp32
    const float* vt = (const float*)d_in[1];   // [2048,4096]   fp32
    const float* uw = (const float*)d_in[2];   // [32,128,64]   fp32
    float* out = (float*)d_out;

    unsigned short* hs_bf = (unsigned short*)d_ws;            // 67108864 bf16
    unsigned short* vt_bf = hs_bf + 67108864L;                //  8388608 bf16
    unsigned short* z_bf  = vt_bf + 8388608L;                 // 33554432 bf16

    cvt_f32_bf16<<<2048, 256, 0, stream>>>(hs, hs_bf, 67108864L);
    cvt_f32_bf16<<<512, 256, 0, stream>>>(vt, vt_bf, 8388608L);

    // GEMM1: (16384/256) x (2048/256) = 64 x 8 = 512 blocks, 512 threads
    gemm1_8ph<<<512, 512, 0, stream>>>(hs_bf, vt_bf, z_bf);

    // GEMM2: (16384/64) x 32 groups = 8192 blocks
    gemm2<<<8192, 256, 0, stream>>>(z_bf, uw, out);
}